// Round 1
// baseline (784.303 us; speedup 1.0000x reference)
//
#include <hip/hip_runtime.h>
#include <stdint.h>

// AAM-Softmax fused: loss + acc for B=1024, C=100000, D=256.
//   K1: normalize emb rows (fp32) -> bf16 in MFMA-A fragment order (ws)
//   K2: per-128-class block: load+normalize weight rows into register B-frags,
//       loop all M: MFMA -> clip -> margin@target -> exp(l-30) row-sums +
//       row-max via atomics. No logits materialized, no row-max pass needed
//       (logits bounded by +-30 so exp(l-30) is always stable).
//   K3: per-row loss = 30 + log(S) - 30*t_target; acc = target attains max.
#define DIM    256
#define BATCH  1024
#define NCLS   100000
#define CBLK   128                      // classes per block = 4 waves * 32
#define NBLK   ((NCLS + CBLK - 1) / CBLK)   // 782 (96 padded classes masked)
#define NCHUNK 16                       // 1024 rows / 64-row LDS chunks
#define CLIPV  0.9999999f               // 1 - 1e-7 (matches ref fp32 clip)
#define COSM   0.98006657784124163f     // cos(0.2)
#define SINM   0.19866933079506122f     // sin(0.2)
#define K30L2E 43.280851226668903f      // 30 * log2(e)

typedef __attribute__((ext_vector_type(8))) short  short8;   // 8 bf16 = 4 VGPR
typedef __attribute__((ext_vector_type(4))) float  floatx4;

// ws layout (644 KB total)
#define EMBF_OFF 0              // 512 KB bf16 emb, fragment order
#define S_OFF    (512 * 1024)   // 64 KB fp32 sumexp, stride 16 floats/row
#define MX_OFF   (576 * 1024)   // 64 KB u32 packed row-max, stride 16/row
#define TL_OFF   (640 * 1024)   // 4 KB fp32 adjusted target cos per row

__device__ __forceinline__ unsigned short f2bf(float f) {
    unsigned u = __float_as_uint(f);
    u += 0x7fffu + ((u >> 16) & 1u);        // RNE; inputs are finite
    return (unsigned short)(u >> 16);
}

// ---------------- K1: normalize embeddings -> bf16 fragments ----------------
__global__ __launch_bounds__(64) void k_norm_emb(
        const float* __restrict__ emb, unsigned short* __restrict__ embf) {
    const int mt  = blockIdx.x;          // M-tile (16 rows), 0..63
    const int l   = threadIdx.x;         // lane 0..63
    const int r16 = l & 15, q = l >> 4;
    const float* rp = emb + (size_t)(mt * 16 + r16) * DIM + q * 8;
    float v[64];
    float ss = 0.f;
#pragma unroll
    for (int s = 0; s < 8; ++s) {        // lane covers k = q*8+j + 32*s
        float4 a = *(const float4*)(rp + 32 * s);
        float4 b = *(const float4*)(rp + 32 * s + 4);
        v[s*8+0]=a.x; v[s*8+1]=a.y; v[s*8+2]=a.z; v[s*8+3]=a.w;
        v[s*8+4]=b.x; v[s*8+5]=b.y; v[s*8+6]=b.z; v[s*8+7]=b.w;
        ss += a.x*a.x + a.y*a.y + a.z*a.z + a.w*a.w;
        ss += b.x*b.x + b.y*b.y + b.z*b.z + b.w*b.w;
    }
    ss += __shfl_xor(ss, 16);            // combine the 4 quads of this row
    ss += __shfl_xor(ss, 32);
    const float sc = 1.f / fmaxf(sqrtf(ss), 1e-12f);
#pragma unroll
    for (int s = 0; s < 8; ++s) {
        unsigned h[8];
#pragma unroll
        for (int j = 0; j < 8; ++j) h[j] = f2bf(v[s*8+j] * sc);
        uint4 u;
        u.x = h[0] | (h[1] << 16);
        u.y = h[2] | (h[3] << 16);
        u.z = h[4] | (h[5] << 16);
        u.w = h[6] | (h[7] << 16);
        // fragment order: [(mt*8+s)*64 + lane] * 16B  -> ds_read_b128 friendly
        *(uint4*)(embf + ((size_t)(mt * 8 + s) * 64 + l) * 8) = u;
    }
}

// ---------------- K2: fused GEMM + online softmax partials ----------------
__global__ __launch_bounds__(256) void k_main(
        const float* __restrict__ wgt, const int* __restrict__ labels,
        const unsigned short* __restrict__ embf,
        float* __restrict__ S, unsigned* __restrict__ MX,
        float* __restrict__ TL) {
    __shared__ __align__(16) unsigned short lds[4 * 8 * 64 * 8];  // 32 KB chunk
    const int tid = threadIdx.x;
    const int w = tid >> 6, l = tid & 63;
    const int r16 = l & 15, q = l >> 4;
    const int cbase = blockIdx.x * CBLK + w * 32;   // wave owns 32 classes

    // --- stage B: raw-bf16 weight fragments in regs + per-class 1/||w|| ---
    short8 bfrag[2][8];
    float  wsc[2];
#pragma unroll
    for (int ct = 0; ct < 2; ++ct) {
        const int cls = cbase + ct * 16 + r16;
        float ss = 0.f;
        if (cls < NCLS) {
            const float* rp = wgt + (size_t)cls * DIM + q * 8;
#pragma unroll
            for (int s = 0; s < 8; ++s) {
                float4 a = *(const float4*)(rp + 32 * s);
                float4 b = *(const float4*)(rp + 32 * s + 4);
                ss += a.x*a.x + a.y*a.y + a.z*a.z + a.w*a.w;
                ss += b.x*b.x + b.y*b.y + b.z*b.z + b.w*b.w;
                bfrag[ct][s][0] = (short)f2bf(a.x);
                bfrag[ct][s][1] = (short)f2bf(a.y);
                bfrag[ct][s][2] = (short)f2bf(a.z);
                bfrag[ct][s][3] = (short)f2bf(a.w);
                bfrag[ct][s][4] = (short)f2bf(b.x);
                bfrag[ct][s][5] = (short)f2bf(b.y);
                bfrag[ct][s][6] = (short)f2bf(b.z);
                bfrag[ct][s][7] = (short)f2bf(b.w);
            }
        } else {
#pragma unroll
            for (int s = 0; s < 8; ++s)
#pragma unroll
                for (int j = 0; j < 8; ++j) bfrag[ct][s][j] = 0;
        }
        ss += __shfl_xor(ss, 16);          // uniform: all quads of a class OOB together
        ss += __shfl_xor(ss, 32);
        wsc[ct] = 1.f / fmaxf(sqrtf(ss), 1e-12f);
    }
    const bool valid0 = (cbase + r16) < NCLS;
    const bool valid1 = (cbase + 16 + r16) < NCLS;

    // --- M loop: 16 chunks of 64 rows ---
    for (int ch = 0; ch < NCHUNK; ++ch) {
        const uint4* src = (const uint4*)embf + (size_t)ch * 2048;
        uint4* dst = (uint4*)lds;
        for (int i = tid; i < 2048; i += 256) dst[i] = src[i];
        __syncthreads();
#pragma unroll
        for (int mtl = 0; mtl < 4; ++mtl) {
            const int mbase = ch * 64 + mtl * 16;
            short8 af[8];
            const short8* lp = (const short8*)lds + (mtl * 8) * 64 + l;
#pragma unroll
            for (int s = 0; s < 8; ++s) af[s] = lp[s * 64];
            floatx4 acc0 = {0.f, 0.f, 0.f, 0.f};
            floatx4 acc1 = {0.f, 0.f, 0.f, 0.f};
#pragma unroll
            for (int s = 0; s < 8; ++s) {
                acc0 = __builtin_amdgcn_mfma_f32_16x16x32_bf16(af[s], bfrag[0][s], acc0, 0, 0, 0);
                acc1 = __builtin_amdgcn_mfma_f32_16x16x32_bf16(af[s], bfrag[1][s], acc1, 0, 0, 0);
            }
            int lbl[4];
#pragma unroll
            for (int r = 0; r < 4; ++r) lbl[r] = labels[mbase + q * 4 + r];
            float sum[4] = {0.f, 0.f, 0.f, 0.f};
            float mx[4]  = {-2.f, -2.f, -2.f, -2.f};
#pragma unroll
            for (int ct = 0; ct < 2; ++ct) {
                const int cls = cbase + ct * 16 + r16;
                const bool valid = ct ? valid1 : valid0;
                const float sc = wsc[ct];
#pragma unroll
                for (int r = 0; r < 4; ++r) {
                    float t = (ct ? acc1[r] : acc0[r]) * sc;     // cos(theta)
                    t = fminf(fmaxf(t, -CLIPV), CLIPV);
                    if (__builtin_expect(cls == lbl[r], 0)) {    // margin @ target
                        t = t * COSM - sqrtf(fmaxf(1.f - t * t, 0.f)) * SINM;
                        TL[mbase + q * 4 + r] = t;
                    }
                    const float p = valid ? exp2f(fmaf(t, K30L2E, -K30L2E)) : 0.f;
                    sum[r] += p;
                    if (valid) mx[r] = fmaxf(mx[r], t);
                }
            }
#pragma unroll
            for (int k = 1; k < 16; k <<= 1) {      // reduce over 16 cols/quad
#pragma unroll
                for (int r = 0; r < 4; ++r) {
                    sum[r] += __shfl_xor(sum[r], k);
                    mx[r] = fmaxf(mx[r], __shfl_xor(mx[r], k));
                }
            }
            if (r16 < 4) {
                float sv = sum[0], mv = mx[0];
                if (r16 == 1) { sv = sum[1]; mv = mx[1]; }
                else if (r16 == 2) { sv = sum[2]; mv = mx[2]; }
                else if (r16 == 3) { sv = sum[3]; mv = mx[3]; }
                const int row = mbase + q * 4 + r16;
                atomicAdd(S + row * 16, sv);                         // 64B stride
                atomicMax(MX + row * 16, __float_as_uint(mv + 2.f)); // order-preserving
            }
        }
        __syncthreads();
    }
}

// ---------------- K3: per-row loss/acc + mean ----------------
__global__ __launch_bounds__(1024) void k_final(
        const float* __restrict__ S, const unsigned* __restrict__ MX,
        const float* __restrict__ TL, float* __restrict__ out) {
    const int t = threadIdx.x;                    // row
    const float s    = S[t * 16];
    const unsigned m = MX[t * 16];
    const float tl   = TL[t];
    float loss = 30.f + logf(s) - 30.f * tl;      // logsumexp - target logit
    float corr = (__float_as_uint(tl + 2.f) >= m) ? 1.f : 0.f;
#pragma unroll
    for (int k = 1; k < 64; k <<= 1) {
        loss += __shfl_xor(loss, k);
        corr += __shfl_xor(corr, k);
    }
    __shared__ float rl[16], rc[16];
    const int w = t >> 6;
    if ((t & 63) == 0) { rl[w] = loss; rc[w] = corr; }
    __syncthreads();
    if (t == 0) {
        float L = 0.f, C = 0.f;
#pragma unroll
        for (int i = 0; i < 16; ++i) { L += rl[i]; C += rc[i]; }
        out[0] = L * (1.f / 1024.f);
        out[1] = C * (1.f / 1024.f);
    }
}

extern "C" void kernel_launch(void* const* d_in, const int* in_sizes, int n_in,
                              void* d_out, int out_size, void* d_ws, size_t ws_size,
                              hipStream_t stream) {
    (void)in_sizes; (void)n_in; (void)out_size; (void)ws_size;
    const float* emb    = (const float*)d_in[0];
    const float* wgt    = (const float*)d_in[1];
    const int*   labels = (const int*)d_in[2];
    char* ws = (char*)d_ws;
    unsigned short* embf = (unsigned short*)(ws + EMBF_OFF);
    float*    S  = (float*)(ws + S_OFF);
    unsigned* MX = (unsigned*)(ws + MX_OFF);
    float*    TL = (float*)(ws + TL_OFF);

    hipMemsetAsync(ws + S_OFF, 0, 128 * 1024, stream);   // zero S + MX
    k_norm_emb<<<64, 64, 0, stream>>>(emb, embf);
    k_main<<<NBLK, 256, 0, stream>>>(wgt, labels, embf, S, MX, TL);
    k_final<<<1, 1024, 0, stream>>>(S, MX, TL, (float*)d_out);
}

// Round 2
// 500.818 us; speedup vs baseline: 1.5660x; 1.5660x over previous
//
#include <hip/hip_runtime.h>
#include <stdint.h>

// AAM-Softmax fused: loss + acc for B=1024, C=100000, D=256.
//   K1: normalize emb rows (fp32) -> bf16 in MFMA-A fragment order (ws)
//   K2: per-128-class block: load+normalize weight rows into register B-frags,
//       loop all 64 M-tiles: A-frags direct from L2-resident embf, MFMA,
//       clip / margin@target / exp(l-30); per-row sums+max accumulated in
//       an LDS[1024] accumulator (LDS atomics, block-local), then ONE
//       coalesced per-block partial slice written to global. No global
//       atomics in the hot path (round-1 lesson: 3100 serialized atomics
//       per address -> 200 MB write traffic -> 818 us).
//   K3: reduce 782 partials per row (coalesced), per-row loss/acc, mean.
#define DIM    256
#define BATCH  1024
#define NCLS   100000
#define CBLK   128                      // classes per block = 4 waves * 32
#define NBLK   ((NCLS + CBLK - 1) / CBLK)   // 782 (96 padded classes masked)
#define CLIPV  0.9999999f               // 1 - 1e-7 (matches ref fp32 clip)
#define COSM   0.98006657784124163f     // cos(0.2)
#define SINM   0.19866933079506122f     // sin(0.2)
#define K30L2E 43.280851226668903f      // 30 * log2(e)

typedef __attribute__((ext_vector_type(8))) short  short8;   // 8 bf16 = 4 VGPR
typedef __attribute__((ext_vector_type(4))) float  floatx4;

// ws layout (~8.3 MB total)
#define EMBF_OFF 0                      // 512 KB bf16 emb, fragment order
#define TL_OFF   (512 * 1024)           // 4 KB fp32 adjusted target cos per row
#define SP_OFF   (1u << 20)             // 782*1024 fp32 partial sumexp (3.2 MB)
#define MP_OFF   (5u << 20)             // 782*1024 u32 partial packed max

__device__ __forceinline__ unsigned short f2bf(float f) {
    unsigned u = __float_as_uint(f);
    u += 0x7fffu + ((u >> 16) & 1u);        // RNE; inputs are finite
    return (unsigned short)(u >> 16);
}

// ---------------- K1: normalize embeddings -> bf16 fragments ----------------
__global__ __launch_bounds__(64) void k_norm_emb(
        const float* __restrict__ emb, unsigned short* __restrict__ embf) {
    const int mt  = blockIdx.x;          // M-tile (16 rows), 0..63
    const int l   = threadIdx.x;         // lane 0..63
    const int r16 = l & 15, q = l >> 4;
    const float* rp = emb + (size_t)(mt * 16 + r16) * DIM + q * 8;
    float v[64];
    float ss = 0.f;
#pragma unroll
    for (int s = 0; s < 8; ++s) {        // lane covers k = q*8+j + 32*s
        float4 a = *(const float4*)(rp + 32 * s);
        float4 b = *(const float4*)(rp + 32 * s + 4);
        v[s*8+0]=a.x; v[s*8+1]=a.y; v[s*8+2]=a.z; v[s*8+3]=a.w;
        v[s*8+4]=b.x; v[s*8+5]=b.y; v[s*8+6]=b.z; v[s*8+7]=b.w;
        ss += a.x*a.x + a.y*a.y + a.z*a.z + a.w*a.w;
        ss += b.x*b.x + b.y*b.y + b.z*b.z + b.w*b.w;
    }
    ss += __shfl_xor(ss, 16);            // combine the 4 quads of this row
    ss += __shfl_xor(ss, 32);
    const float sc = 1.f / fmaxf(sqrtf(ss), 1e-12f);
#pragma unroll
    for (int s = 0; s < 8; ++s) {
        unsigned h[8];
#pragma unroll
        for (int j = 0; j < 8; ++j) h[j] = f2bf(v[s*8+j] * sc);
        uint4 u;
        u.x = h[0] | (h[1] << 16);
        u.y = h[2] | (h[3] << 16);
        u.z = h[4] | (h[5] << 16);
        u.w = h[6] | (h[7] << 16);
        // fragment order: [(mt*8+s)*64 + lane] * 16B  -> dwordx4 friendly
        *(uint4*)(embf + ((size_t)(mt * 8 + s) * 64 + l) * 8) = u;
    }
}

// ---------------- K2: fused GEMM + online softmax partials ----------------
__global__ __launch_bounds__(256) void k_main(
        const float* __restrict__ wgt, const int* __restrict__ labels,
        const unsigned short* __restrict__ embf,
        float* __restrict__ SP, unsigned* __restrict__ MP,
        float* __restrict__ TL) {
    __shared__ float    rs[1024];        // per-row sumexp accumulator
    __shared__ unsigned rm[1024];        // per-row packed-max accumulator
    __shared__ int      llab[1024];      // labels (kills 12.8M global loads)
    const int tid = threadIdx.x;
    for (int i = tid; i < 1024; i += 256) {
        rs[i] = 0.f; rm[i] = 0u; llab[i] = labels[i];
    }
    const int w = tid >> 6, l = tid & 63;
    const int r16 = l & 15, q = l >> 4;
    const int cbase = blockIdx.x * CBLK + w * 32;   // wave owns 32 classes

    // --- stage B: raw-bf16 weight fragments in regs + per-class 1/||w|| ---
    short8 bfrag[2][8];
    float  wsc[2];
#pragma unroll
    for (int ct = 0; ct < 2; ++ct) {
        const int cls = cbase + ct * 16 + r16;
        float ss = 0.f;
        if (cls < NCLS) {
            const float* rp = wgt + (size_t)cls * DIM + q * 8;
#pragma unroll
            for (int s = 0; s < 8; ++s) {
                float4 a = *(const float4*)(rp + 32 * s);
                float4 b = *(const float4*)(rp + 32 * s + 4);
                ss += a.x*a.x + a.y*a.y + a.z*a.z + a.w*a.w;
                ss += b.x*b.x + b.y*b.y + b.z*b.z + b.w*b.w;
                bfrag[ct][s][0] = (short)f2bf(a.x);
                bfrag[ct][s][1] = (short)f2bf(a.y);
                bfrag[ct][s][2] = (short)f2bf(a.z);
                bfrag[ct][s][3] = (short)f2bf(a.w);
                bfrag[ct][s][4] = (short)f2bf(b.x);
                bfrag[ct][s][5] = (short)f2bf(b.y);
                bfrag[ct][s][6] = (short)f2bf(b.z);
                bfrag[ct][s][7] = (short)f2bf(b.w);
            }
        } else {
#pragma unroll
            for (int s = 0; s < 8; ++s)
#pragma unroll
                for (int j = 0; j < 8; ++j) bfrag[ct][s][j] = 0;
        }
        ss += __shfl_xor(ss, 16);          // uniform: quads of a class OOB together
        ss += __shfl_xor(ss, 32);
        wsc[ct] = 1.f / fmaxf(sqrtf(ss), 1e-12f);
    }
    const bool valid0 = (cbase + r16) < NCLS;
    const bool valid1 = (cbase + 16 + r16) < NCLS;

    __syncthreads();                     // LDS init visible to all waves

    // --- M loop: 64 tiles of 16 rows, barrier-free ---
    for (int mt = 0; mt < 64; ++mt) {
        // A-frags straight from global (embf is 512 KB -> L2-resident,
        // same addresses for every block -> broadcast hits)
        const short8* ap = (const short8*)embf + (size_t)(mt * 8) * 64 + l;
        short8 af[8];
#pragma unroll
        for (int s = 0; s < 8; ++s) af[s] = ap[s * 64];
        floatx4 acc0 = {0.f, 0.f, 0.f, 0.f};
        floatx4 acc1 = {0.f, 0.f, 0.f, 0.f};
#pragma unroll
        for (int s = 0; s < 8; ++s) {
            acc0 = __builtin_amdgcn_mfma_f32_16x16x32_bf16(af[s], bfrag[0][s], acc0, 0, 0, 0);
            acc1 = __builtin_amdgcn_mfma_f32_16x16x32_bf16(af[s], bfrag[1][s], acc1, 0, 0, 0);
        }
        const int mbase = mt * 16;
        int lbl[4];
#pragma unroll
        for (int r = 0; r < 4; ++r) lbl[r] = llab[mbase + q * 4 + r];
        float sum[4] = {0.f, 0.f, 0.f, 0.f};
        float mx[4]  = {-2.f, -2.f, -2.f, -2.f};
#pragma unroll
        for (int ct = 0; ct < 2; ++ct) {
            const int cls = cbase + ct * 16 + r16;
            const bool valid = ct ? valid1 : valid0;
            const float sc = wsc[ct];
#pragma unroll
            for (int r = 0; r < 4; ++r) {
                float t = (ct ? acc1[r] : acc0[r]) * sc;     // cos(theta)
                t = fminf(fmaxf(t, -CLIPV), CLIPV);
                if (__builtin_expect(cls == lbl[r], 0)) {    // margin @ target
                    t = t * COSM - sqrtf(fmaxf(1.f - t * t, 0.f)) * SINM;
                    TL[mbase + q * 4 + r] = t;
                }
                const float p = valid ? exp2f(fmaf(t, K30L2E, -K30L2E)) : 0.f;
                sum[r] += p;
                if (valid) mx[r] = fmaxf(mx[r], t);
            }
        }
#pragma unroll
        for (int k = 1; k < 16; k <<= 1) {      // reduce over 16 cols/quad
#pragma unroll
            for (int r = 0; r < 4; ++r) {
                sum[r] += __shfl_xor(sum[r], k);
                mx[r] = fmaxf(mx[r], __shfl_xor(mx[r], k));
            }
        }
        if (r16 < 4) {
            float sv = sum[0], mv = mx[0];
            if (r16 == 1) { sv = sum[1]; mv = mx[1]; }
            else if (r16 == 2) { sv = sum[2]; mv = mx[2]; }
            else if (r16 == 3) { sv = sum[3]; mv = mx[3]; }
            const int row = mbase + q * 4 + r16;
            atomicAdd(&rs[row], sv);                          // LDS atomics:
            atomicMax(&rm[row], __float_as_uint(mv + 2.f));   // 4-way max contention
        }
    }

    __syncthreads();
    // one contention-free, coalesced partial slice per block
    float*    sp = SP + (size_t)blockIdx.x * 1024;
    unsigned* mp = MP + (size_t)blockIdx.x * 1024;
    for (int i = tid; i < 1024; i += 256) { sp[i] = rs[i]; mp[i] = rm[i]; }
}

// ---------------- K3: reduce partials + per-row loss/acc + mean ----------------
__global__ __launch_bounds__(128) void k_final(
        const float* __restrict__ SP, const unsigned* __restrict__ MP,
        const float* __restrict__ TL, float* __restrict__ out) {
    const int row = blockIdx.x * 128 + threadIdx.x;
    float s = 0.f;
    unsigned m = 0u;
#pragma unroll 4
    for (int b = 0; b < NBLK; ++b) {     // coalesced: threads = consecutive rows
        s += SP[(size_t)b * 1024 + row];
        const unsigned v = MP[(size_t)b * 1024 + row];
        m = v > m ? v : m;
    }
    const float tl = TL[row];
    float loss = 30.f + logf(s) - 30.f * tl;      // logsumexp - target logit
    float corr = (__float_as_uint(tl + 2.f) >= m) ? 1.f : 0.f;
#pragma unroll
    for (int k = 1; k < 64; k <<= 1) {
        loss += __shfl_xor(loss, k);
        corr += __shfl_xor(corr, k);
    }
    __shared__ float rl[2], rc[2];
    if ((threadIdx.x & 63) == 0) { rl[threadIdx.x >> 6] = loss; rc[threadIdx.x >> 6] = corr; }
    __syncthreads();
    if (threadIdx.x == 0) {
        atomicAdd(out + 0, (rl[0] + rl[1]) * (1.f / 1024.f));
        atomicAdd(out + 1, (rc[0] + rc[1]) * (1.f / 1024.f));
    }
}

extern "C" void kernel_launch(void* const* d_in, const int* in_sizes, int n_in,
                              void* d_out, int out_size, void* d_ws, size_t ws_size,
                              hipStream_t stream) {
    (void)in_sizes; (void)n_in; (void)out_size; (void)ws_size;
    const float* emb    = (const float*)d_in[0];
    const float* wgt    = (const float*)d_in[1];
    const int*   labels = (const int*)d_in[2];
    char* ws = (char*)d_ws;
    unsigned short* embf = (unsigned short*)(ws + EMBF_OFF);
    float*    TL = (float*)(ws + TL_OFF);
    float*    SP = (float*)(ws + SP_OFF);
    unsigned* MP = (unsigned*)(ws + MP_OFF);

    hipMemsetAsync(d_out, 0, 2 * sizeof(float), stream);   // K3 accumulates into out
    k_norm_emb<<<64, 64, 0, stream>>>(emb, embf);
    k_main<<<NBLK, 256, 0, stream>>>(wgt, labels, embf, SP, MP, TL);
    k_final<<<8, 128, 0, stream>>>(SP, MP, TL, (float*)d_out);
}